// Round 7
// baseline (2918.080 us; speedup 1.0000x reference)
//
#include <hip/hip_runtime.h>
#include <stdint.h>

#define NTOT   12288
#define NW     192           // NTOT/64 bit-words
#define NCH    6
#define NCHUNK 12
#define CSZ    1024          // boxes per chunk
#define CWRD   16            // words per chunk
#define NBLK   224           // co-resident blocks (1/CU forced by LDS)
#define CONF_THR 0.01f
#define NMS_THR  0.45f

typedef unsigned long long u64;
typedef uint32_t u32;

__device__ __forceinline__ float sigmf(float x){ return 1.0f/(1.0f+expf(-x)); }

// exact reference IoU-suppression test
__device__ __forceinline__ bool sup_pair(float ax1,float ay1,float ax2,float ay2,float aar,
                                         float bx1,float by1,float bx2,float by2,float bar){
  float tlx=fmaxf(ax1,bx1), tly=fmaxf(ay1,by1);
  float brx=fminf(ax2,bx2), bry=fminf(ay2,by2);
  float inter=(brx-tlx)*(bry-tly);
  if(!(tlx<brx && tly<bry)) inter=0.0f;
  float iou = inter/((aar+bar)-inter);
  return iou >= NMS_THR;
}

__device__ __forceinline__ u64 rfl64(u64 v){
  u32 lo = (u32)__builtin_amdgcn_readfirstlane((int)(u32)(v & 0xffffffffull));
  u32 hi = (u32)__builtin_amdgcn_readfirstlane((int)(u32)(v>>32));
  return (((u64)hi)<<32) | (u64)lo;
}
__device__ __forceinline__ u64 rdlane64(u64 v, int src){
  u32 lo = (u32)__builtin_amdgcn_readlane((int)(u32)(v & 0xffffffffull), src);
  u32 hi = (u32)__builtin_amdgcn_readlane((int)(u32)(v>>32), src);
  return (((u64)hi)<<32) | (u64)lo;
}
__device__ __forceinline__ void dma16(const void* g, void* l){
  __builtin_amdgcn_global_load_lds((const __attribute__((address_space(1))) void*)g,
                                   (__attribute__((address_space(3))) void*)l, 16, 0, 0);
}

// manual grid barrier: safe because all NBLK blocks are co-resident (1 block/CU by LDS)
__device__ __forceinline__ void gbar(u32* cnt, u32* gen, u32 nblk){
  __syncthreads();                          // drains vmcnt(0): all block writes complete
  if(threadIdx.x==0){
    u32 g = __hip_atomic_load(gen, __ATOMIC_ACQUIRE, __HIP_MEMORY_SCOPE_AGENT);
    if(atomicAdd(cnt,1u) == nblk-1u){
      atomicAnd(cnt,0u);
      __threadfence();                      // reset lands before gen bump
      atomicAdd(gen,1u);
    } else {
      while(__hip_atomic_load(gen, __ATOMIC_ACQUIRE, __HIP_MEMORY_SCOPE_AGENT)==g)
        __builtin_amdgcn_s_sleep(32);
    }
  }
  __syncthreads();
}

// ---------------- decode ----------------
__global__ void k_decode(const float* __restrict__ feat, const float* __restrict__ anchors,
                         float4* __restrict__ obox, float* __restrict__ oobj,
                         float* __restrict__ ocls, float* __restrict__ oscore,
                         u32* __restrict__ okey, int* __restrict__ rank){
  int n = blockIdx.x*256 + threadIdx.x;
  int a = n >> 12;
  int cell = n & 4095;
  int gy = cell >> 6, gx = cell & 63;
  const float* f = feat + a*NCH*4096 + cell;
  float v0=f[0], v1=f[4096], v2=f[8192], v3=f[12288], v4=f[16384], v5=f[20480];
  float aw = anchors[2*a]   * 0.125f;
  float ah = anchors[2*a+1] * 0.125f;
  float px = (sigmf(v0) + (float)gx) * 8.0f;
  float py = (sigmf(v1) + (float)gy) * 8.0f;
  float pw = (expf(v2)*aw) * 8.0f;
  float ph = (expf(v3)*ah) * 8.0f;
  float obj = sigmf(v4), cls = sigmf(v5);
  float4 b;
  b.x = px - pw*0.5f; b.y = py - ph*0.5f;
  b.z = px + pw*0.5f; b.w = py + ph*0.5f;
  float sc = obj*cls;
  obox[n]=b; oobj[n]=obj; ocls[n]=cls; oscore[n]=sc;
  u32 u = __float_as_uint(sc);
  u32 asc = (u & 0x80000000u) ? ~u : (u | 0x80000000u);
  okey[n] = ~asc;            // descending: higher score -> smaller key
  rank[n] = 0;
}

// ---------------- partial rank over a 1024-key slice ----------------
__global__ __launch_bounds__(256) void k_rank_part(const u32* __restrict__ okey,
                                                   int* __restrict__ rank){
  __shared__ u32 tile[1024];
  int n = blockIdx.x*256 + threadIdx.x;
  int t0 = blockIdx.y * 1024;
  u32 my = okey[n];
  for(int k=threadIdx.x;k<1024;k+=256) tile[k]=okey[t0+k];
  __syncthreads();
  int r0=0,r1=0,r2=0,r3=0;
  #pragma unroll 4
  for(int k=0;k<1024;k+=4){
    uint4 kj = *reinterpret_cast<const uint4*>(&tile[k]);
    int j = t0+k;
    r0 += (int)((kj.x<my)||(kj.x==my && (j  )<n));
    r1 += (int)((kj.y<my)||(kj.y==my && (j+1)<n));
    r2 += (int)((kj.z<my)||(kj.z==my && (j+2)<n));
    r3 += (int)((kj.w<my)||(kj.w==my && (j+3)<n));
  }
  atomicAdd(&rank[n], r0+r1+r2+r3);
}

// ---------------- scatter into sorted arrays + zero NMS state ----------------
__global__ void k_scatter(const int* __restrict__ rank,
                          const float4* __restrict__ obox,const float* __restrict__ oobj,
                          const float* __restrict__ ocls,const float* __restrict__ oscore,
                          float4* __restrict__ sbox,float* __restrict__ sarea,
                          float* __restrict__ sobj,float* __restrict__ scls,
                          u32* __restrict__ svalid,int* __restrict__ order,
                          u64* presupG,u64* keepw,u32* bar){
  int n = blockIdx.x*256 + threadIdx.x;
  if(blockIdx.x==0){
    if(threadIdx.x<NW){ presupG[threadIdx.x]=0ull; keepw[threadIdx.x]=0ull; }
    if(threadIdx.x<2)  bar[threadIdx.x]=0u;
  }
  int r = rank[n];
  float4 b = obox[n];
  sbox[r]=b;
  sarea[r]=(b.z-b.x)*(b.w-b.y);
  sobj[r]=oobj[n]; scls[r]=ocls[n];
  svalid[r] = (oscore[n] >= CONF_THR) ? 1u : 0u;
  order[r]=n;
}

// ---------------- intra-chunk rows (XOR-swizzled columns): 6.3M pairs total ----------------
__global__ __launch_bounds__(256) void k_rowsC(const float4* __restrict__ sbox,
                       const float* __restrict__ sarea, u64* __restrict__ rowsC){
  int i   = (blockIdx.x*256 + threadIdx.x) >> 6;   // global sorted row = wave id
  int lane = threadIdx.x & 63;
  int cbase = i & ~(CSZ-1);
  float4 a = sbox[i];
  float aar = sarea[i];
  for(int w=0; w<CWRD; ++w){
    int j = cbase + (w<<6) + lane;
    float4 b = sbox[j];
    bool s = (j>i) && sup_pair(a.x,a.y,a.z,a.w,aar, b.x,b.y,b.z,b.w,sarea[j]);
    u64 word = __ballot(s);
    if(lane==w) rowsC[(size_t)i*CWRD + (w ^ (i&15))] = word;  // swizzled column
  }
}

// ---------------- chunked greedy NMS: 1 co-resident grid, manual barriers ----------------
__global__ __launch_bounds__(256,1) void k_nms(
    const float4* __restrict__ sbox, const float* __restrict__ sarea,
    const u32* __restrict__ svalid, const u64* __restrict__ rowsC,
    u64* presupG, u64* keepw, u32* bar)
{
  __shared__ __align__(16) char smem[153376];
  u64* rowsL    = (u64*)smem;                        // [CSZ*CWRD] = 128 KB (block 0)
  u64* validwL  = (u64*)(smem+131072);               // [NW]
  volatile u64* maskL = (volatile u64*)(smem+132608);// [CWRD]
  u64* kwL      = (u64*)(smem+132736);               // [CWRD]
  u32* cntL     = (u32*)(smem+132864);
  float* fwdAr  = (float*)(smem+132880);             // [CSZ]
  float4* fwdBox= (float4*)(smem+136992);            // [CSZ]
  int tid=threadIdx.x, lane=tid&63, wv=tid>>6, bid=blockIdx.x;

  if(bid==0){
    // valid words (per-chunk resolve input)
    for(int w=wv; w<NW; w+=4){
      u32 sv = svalid[w*64+lane];
      u64 b = __ballot(sv!=0u);
      if(lane==0) validwL[w]=b;
    }
    // stage chunk 0 rows (128 KB) into LDS
    const char* src = (const char*)rowsC;
    for(int k=0;k<32;k++)
      dma16(src + (size_t)(tid+k*256)*16, (char*)smem + (size_t)(tid+k*256)*16);
    asm volatile("s_waitcnt vmcnt(0)" ::: "memory");
    __syncthreads();
  }

  for(int c=0;c<NCHUNK;c++){
    // -------- resolve chunk c (block 0, wave 0 serial core) --------
    if(bid==0){
      if(tid<CWRD) maskL[tid] = atomicOr(&presupG[c*CWRD+tid],0ull) | ~validwL[c*CWRD+tid];
      __syncthreads();
      if(tid<64){
        for(int w=0; w<CWRD; ++w){
          u64 rowl = rowsL[(size_t)((w<<6)+lane)*CWRD + (w ^ (lane&15))];
          u64 cand = rfl64(~maskL[w]);
          u64 keep64 = 0;
          while(cand){
            unsigned t = (unsigned)__builtin_ctzll(cand);
            keep64 |= (1ull<<t);
            cand &= ~(1ull<<t);
            cand &= ~rdlane64(rowl,(int)t);
          }
          if(lane==0) atomicExch(&keepw[c*CWRD+w], keep64);
          if(lane<CWRD){                       // apply kept rows to chunk words
            u64 kk=keep64, acc=0;
            while(kk){
              int t=__builtin_ctzll(kk); kk&=kk-1ull;
              acc |= rowsL[(size_t)((w<<6)+t)*CWRD + (lane ^ (t&15))];
            }
            maskL[lane] = maskL[lane] | acc;
          }
          asm volatile("s_waitcnt lgkmcnt(0)" ::: "memory");
          __builtin_amdgcn_sched_barrier(0);
        }
      }
    }
    gbar(bar, bar+1, NBLK);
    // -------- prefetch next chunk's rows (hidden under forward) --------
    if(bid==0 && c+1<NCHUNK){
      const char* src = (const char*)rowsC + (size_t)(c+1)*CSZ*CWRD*8;
      for(int k=0;k<32;k++)
        dma16(src + (size_t)(tid+k*256)*16, (char*)smem + (size_t)(tid+k*256)*16);
    }
    // -------- forward: suppress later boxes vs chunk c kept (all blocks) --------
    if(tid==0) *cntL=0u;
    if(tid<CWRD) kwL[tid] = atomicOr(&keepw[c*CWRD+tid],0ull);
    __syncthreads();
    for(int i=tid;i<CSZ;i+=256){
      if((kwL[i>>6]>>(unsigned)(i&63))&1ull){
        u32 p = atomicAdd(cntL,1u);
        fwdBox[p]=sbox[c*CSZ+i];
        fwdAr[p]=sarea[c*CSZ+i];
      }
    }
    __syncthreads();
    int kc=(int)*cntL;
    for(int j=(c+1)*CSZ + bid*256 + tid; j<NTOT; j+=NBLK*256){
      u64 pw = presupG[j>>6];               // stale-tolerant: bits only accumulate
      bool sup=false;
      if(!((pw>>(unsigned)(j&63))&1ull)){
        float4 b=sbox[j]; float ar_=sarea[j];
        for(int r=0;r<kc;r++){
          float4 a=fwdBox[r];
          if(sup_pair(a.x,a.y,a.z,a.w,fwdAr[r], b.x,b.y,b.z,b.w,ar_)){sup=true;break;}
        }
      }
      u64 m=__ballot(sup);
      if(lane==0 && m) atomicOr(&presupG[j>>6], m);  // wave owns its 64-aligned word
    }
    gbar(bar, bar+1, NBLK);                 // also drains block 0's row prefetch
  }
}

// ---------------- final output ----------------
__global__ void k_final(const int* __restrict__ order,const u64* __restrict__ keepw,
                        const float4* __restrict__ sbox,const float* __restrict__ sobj,
                        const float* __restrict__ scls,float* __restrict__ out){
  int i = blockIdx.x*256 + threadIdx.x;
  int n = order[i];
  u64 kw = keepw[i>>6];
  float kf = ((kw>>(unsigned)(i&63))&1ull) ? 1.0f : 0.0f;
  float4 b = sbox[i];
  float* det = out + (size_t)n*6;
  det[0]=b.x*kf; det[1]=b.y*kf; det[2]=b.z*kf; det[3]=b.w*kf;
  det[4]=sobj[i]*kf; det[5]=scls[i]*kf;
  out[NTOT*6 + n] = kf;
}

extern "C" void kernel_launch(void* const* d_in,const int* in_sizes,int n_in,
                              void* d_out,int out_size,void* d_ws,size_t ws_size,
                              hipStream_t stream){
  const float* feat=(const float*)d_in[0];
  const float* anchors=(const float*)d_in[1];
  float* out=(float*)d_out;

  char* w=(char*)d_ws;
  auto alloc=[&](size_t bytes)->char*{ char* p=w; w += (bytes+255)&~255ull; return p; };
  float4 *obox =(float4*)alloc(NTOT*16);
  float  *oobj =(float*) alloc(NTOT*4);
  float  *ocls =(float*) alloc(NTOT*4);
  float  *oscore=(float*)alloc(NTOT*4);
  u32    *okey =(u32*)   alloc(NTOT*4);
  int    *rank =(int*)   alloc(NTOT*4);
  float4 *sbox =(float4*)alloc(NTOT*16);
  float  *sarea=(float*) alloc(NTOT*4);
  float  *sobj =(float*) alloc(NTOT*4);
  float  *scls =(float*) alloc(NTOT*4);
  u32    *svalid=(u32*)  alloc(NTOT*4);
  int    *order=(int*)   alloc(NTOT*4);
  u64    *presupG=(u64*) alloc(NW*8);
  u64    *keepw  =(u64*) alloc(NW*8);
  u32    *bar    =(u32*) alloc(256);
  u64    *rowsC  =(u64*) alloc((size_t)NTOT*CWRD*8);   // 1.5 MB intra-chunk rows

  hipLaunchKernelGGL(k_decode, dim3(NTOT/256),dim3(256),0,stream,
                     feat,anchors,obox,oobj,ocls,oscore,okey,rank);
  hipLaunchKernelGGL(k_rank_part, dim3(NTOT/256,12),dim3(256),0,stream, okey,rank);
  hipLaunchKernelGGL(k_scatter, dim3(NTOT/256),dim3(256),0,stream,
                     rank,obox,oobj,ocls,oscore,sbox,sarea,sobj,scls,svalid,order,
                     presupG,keepw,bar);
  hipLaunchKernelGGL(k_rowsC, dim3(NTOT/4),dim3(256),0,stream, sbox,sarea,rowsC);
  hipLaunchKernelGGL(k_nms, dim3(NBLK),dim3(256),0,stream,
                     sbox,sarea,svalid,rowsC,presupG,keepw,bar);
  hipLaunchKernelGGL(k_final, dim3(NTOT/256),dim3(256),0,stream,
                     order,keepw,sbox,sobj,scls,out);
}

// Round 8
// 2710.477 us; speedup vs baseline: 1.0766x; 1.0766x over previous
//
#include <hip/hip_runtime.h>
#include <stdint.h>

#define NTOT   12288
#define NW     192           // NTOT/64 bit-words
#define NCH    6
#define NCHUNK 12
#define CSZ    1024          // boxes per chunk
#define CWRD   16            // words per chunk
#define CONF_THR 0.01f
#define NMS_THR  0.45f

typedef unsigned long long u64;
typedef uint32_t u32;

__device__ __forceinline__ float sigmf(float x){ return 1.0f/(1.0f+expf(-x)); }

// exact reference IoU-suppression test
__device__ __forceinline__ bool sup_pair(float ax1,float ay1,float ax2,float ay2,float aar,
                                         float bx1,float by1,float bx2,float by2,float bar){
  float tlx=fmaxf(ax1,bx1), tly=fmaxf(ay1,by1);
  float brx=fminf(ax2,bx2), bry=fminf(ay2,by2);
  float inter=(brx-tlx)*(bry-tly);
  if(!(tlx<brx && tly<bry)) inter=0.0f;
  float iou = inter/((aar+bar)-inter);
  return iou >= NMS_THR;
}

__device__ __forceinline__ u64 rfl64(u64 v){
  u32 lo = (u32)__builtin_amdgcn_readfirstlane((int)(u32)(v & 0xffffffffull));
  u32 hi = (u32)__builtin_amdgcn_readfirstlane((int)(u32)(v>>32));
  return (((u64)hi)<<32) | (u64)lo;
}
__device__ __forceinline__ u64 rdlane64(u64 v, int src){
  u32 lo = (u32)__builtin_amdgcn_readlane((int)(u32)(v & 0xffffffffull), src);
  u32 hi = (u32)__builtin_amdgcn_readlane((int)(u32)(v>>32), src);
  return (((u64)hi)<<32) | (u64)lo;
}
__device__ __forceinline__ void dma16(const void* g, void* l){
  __builtin_amdgcn_global_load_lds((const __attribute__((address_space(1))) void*)g,
                                   (__attribute__((address_space(3))) void*)l, 16, 0, 0);
}

// ---------------- decode ----------------
__global__ void k_decode(const float* __restrict__ feat, const float* __restrict__ anchors,
                         float4* __restrict__ obox, float* __restrict__ oobj,
                         float* __restrict__ ocls, float* __restrict__ oscore,
                         u32* __restrict__ okey, int* __restrict__ rank){
  int n = blockIdx.x*256 + threadIdx.x;
  int a = n >> 12;
  int cell = n & 4095;
  int gy = cell >> 6, gx = cell & 63;
  const float* f = feat + a*NCH*4096 + cell;
  float v0=f[0], v1=f[4096], v2=f[8192], v3=f[12288], v4=f[16384], v5=f[20480];
  float aw = anchors[2*a]   * 0.125f;
  float ah = anchors[2*a+1] * 0.125f;
  float px = (sigmf(v0) + (float)gx) * 8.0f;
  float py = (sigmf(v1) + (float)gy) * 8.0f;
  float pw = (expf(v2)*aw) * 8.0f;
  float ph = (expf(v3)*ah) * 8.0f;
  float obj = sigmf(v4), cls = sigmf(v5);
  float4 b;
  b.x = px - pw*0.5f; b.y = py - ph*0.5f;
  b.z = px + pw*0.5f; b.w = py + ph*0.5f;
  float sc = obj*cls;
  obox[n]=b; oobj[n]=obj; ocls[n]=cls; oscore[n]=sc;
  u32 u = __float_as_uint(sc);
  u32 asc = (u & 0x80000000u) ? ~u : (u | 0x80000000u);
  okey[n] = ~asc;            // descending: higher score -> smaller key
  rank[n] = 0;
}

// ---------------- partial rank over a 1024-key slice ----------------
__global__ __launch_bounds__(256) void k_rank_part(const u32* __restrict__ okey,
                                                   int* __restrict__ rank){
  __shared__ u32 tile[1024];
  int n = blockIdx.x*256 + threadIdx.x;
  int t0 = blockIdx.y * 1024;
  u32 my = okey[n];
  for(int k=threadIdx.x;k<1024;k+=256) tile[k]=okey[t0+k];
  __syncthreads();
  int r0=0,r1=0,r2=0,r3=0;
  #pragma unroll 4
  for(int k=0;k<1024;k+=4){
    uint4 kj = *reinterpret_cast<const uint4*>(&tile[k]);
    int j = t0+k;
    r0 += (int)((kj.x<my)||(kj.x==my && (j  )<n));
    r1 += (int)((kj.y<my)||(kj.y==my && (j+1)<n));
    r2 += (int)((kj.z<my)||(kj.z==my && (j+2)<n));
    r3 += (int)((kj.w<my)||(kj.w==my && (j+3)<n));
  }
  atomicAdd(&rank[n], r0+r1+r2+r3);
}

// ---------------- scatter into sorted arrays + zero NMS state ----------------
__global__ void k_scatter(const int* __restrict__ rank,
                          const float4* __restrict__ obox,const float* __restrict__ oobj,
                          const float* __restrict__ ocls,const float* __restrict__ oscore,
                          float4* __restrict__ sbox,float* __restrict__ sarea,
                          float* __restrict__ sobj,float* __restrict__ scls,
                          u32* __restrict__ svalid,int* __restrict__ order,
                          u64* presupG){
  int n = blockIdx.x*256 + threadIdx.x;
  if(blockIdx.x==0 && threadIdx.x<NW) presupG[threadIdx.x]=0ull;
  int r = rank[n];
  float4 b = obox[n];
  sbox[r]=b;
  sarea[r]=(b.z-b.x)*(b.w-b.y);
  sobj[r]=oobj[n]; scls[r]=ocls[n];
  svalid[r] = (oscore[n] >= CONF_THR) ? 1u : 0u;
  order[r]=n;
}

// ---------------- intra-chunk rows (XOR-swizzled columns) ----------------
__global__ __launch_bounds__(256) void k_rowsC(const float4* __restrict__ sbox,
                       const float* __restrict__ sarea, u64* __restrict__ rowsC){
  int i   = (blockIdx.x*256 + threadIdx.x) >> 6;   // global sorted row = wave id
  int lane = threadIdx.x & 63;
  int cbase = i & ~(CSZ-1);
  float4 a = sbox[i];
  float aar = sarea[i];
  for(int w=0; w<CWRD; ++w){
    int j = cbase + (w<<6) + lane;
    float4 b = sbox[j];
    bool s = (j>i) && sup_pair(a.x,a.y,a.z,a.w,aar, b.x,b.y,b.z,b.w,sarea[j]);
    u64 word = __ballot(s);
    if(lane==w) rowsC[(size_t)i*CWRD + (w ^ (i&15))] = word;  // swizzled column
  }
}

// ---------------- resolve one chunk: 1 block, LDS-resident bit-matrix ----------------
__global__ __launch_bounds__(256) void k_resolve(const u64* __restrict__ rowsC,
                       const u32* __restrict__ svalid, const u64* __restrict__ presupG,
                       u64* __restrict__ keepw, int c){
  __shared__ __align__(16) u64 rowsL[CSZ*CWRD];    // 128 KB
  __shared__ u64 maskI[CWRD];
  int tid=threadIdx.x, lane=tid&63, wv=tid>>6;
  // stage chunk rows -> LDS (DMA, in flight during maskI computation)
  {
    const char* src = (const char*)(rowsC + (size_t)c*CSZ*CWRD);
    char* dst = (char*)rowsL;
    #pragma unroll
    for(int k=0;k<32;k++)
      dma16(src + (size_t)(tid+k*256)*16, dst + (size_t)(tid+k*256)*16);
  }
  // init mask = presup | ~valid (4 words per wave)
  #pragma unroll
  for(int q=0;q<4;q++){
    int w = wv*4+q;
    u32 sv = svalid[c*CSZ + w*64 + lane];
    u64 vb = __ballot(sv!=0u);
    if(lane==0) maskI[w] = presupG[c*CWRD+w] | ~vb;
  }
  asm volatile("s_waitcnt vmcnt(0)" ::: "memory");
  __syncthreads();
  if(wv==0){
    volatile u64* maskL = maskI;
    for(int w=0; w<CWRD; ++w){
      u64 rowl = rowsL[(size_t)((w<<6)+lane)*CWRD + (w ^ (lane&15))];
      u64 cand = rfl64(~maskL[w]);
      u64 keep64 = 0;
      while(cand){
        unsigned t = (unsigned)__builtin_ctzll(cand);
        keep64 |= (1ull<<t);
        cand &= ~(1ull<<t);
        cand &= ~rdlane64(rowl,(int)t);
      }
      if(lane==0) keepw[c*CWRD+w] = keep64;
      if(lane<CWRD){                         // apply kept rows to later chunk words
        u64 kk=keep64, acc=0;
        while(kk){
          int t=__builtin_ctzll(kk); kk&=kk-1ull;
          acc |= rowsL[(size_t)((w<<6)+t)*CWRD + (lane ^ (t&15))];
        }
        maskL[lane] = maskL[lane] | acc;
      }
      asm volatile("s_waitcnt lgkmcnt(0)" ::: "memory");
      __builtin_amdgcn_sched_barrier(0);
    }
  }
}

// ---------------- forward: suppress all later boxes vs chunk c's kept ----------------
__global__ __launch_bounds__(256) void k_fwd(const float4* __restrict__ sbox,
                       const float* __restrict__ sarea, const u64* __restrict__ keepw,
                       u64* __restrict__ presupG, int c){
  __shared__ float4 fb[CSZ];
  __shared__ float  fa[CSZ];
  __shared__ u32 cnt;
  int tid=threadIdx.x, lane=tid&63;
  if(tid==0) cnt=0u;
  __syncthreads();
  for(int i=tid;i<CSZ;i+=256){
    if((keepw[c*CWRD + (i>>6)] >> (unsigned)(i&63)) & 1ull){
      u32 p = atomicAdd(&cnt,1u);
      fb[p]=sbox[c*CSZ+i]; fa[p]=sarea[c*CSZ+i];
    }
  }
  __syncthreads();
  int kc=(int)cnt;
  int j = (c+1)*CSZ + blockIdx.x*256 + tid;   // grid sized exactly; j<NTOT always
  u64 pw = presupG[j>>6];
  bool sup=false;
  if(!((pw>>(unsigned)(j&63))&1ull)){
    float4 b=sbox[j]; float ar_=sarea[j];
    for(int r=0;r<kc;r++){
      float4 a=fb[r];
      if(sup_pair(a.x,a.y,a.z,a.w,fa[r], b.x,b.y,b.z,b.w,ar_)){sup=true;break;}
    }
  }
  u64 m=__ballot(sup);
  if(lane==0 && m) atomicOr(&presupG[j>>6], m);   // one wave per 64-aligned word
}

// ---------------- final output ----------------
__global__ void k_final(const int* __restrict__ order,const u64* __restrict__ keepw,
                        const float4* __restrict__ sbox,const float* __restrict__ sobj,
                        const float* __restrict__ scls,float* __restrict__ out){
  int i = blockIdx.x*256 + threadIdx.x;
  int n = order[i];
  u64 kw = keepw[i>>6];
  float kf = ((kw>>(unsigned)(i&63))&1ull) ? 1.0f : 0.0f;
  float4 b = sbox[i];
  float* det = out + (size_t)n*6;
  det[0]=b.x*kf; det[1]=b.y*kf; det[2]=b.z*kf; det[3]=b.w*kf;
  det[4]=sobj[i]*kf; det[5]=scls[i]*kf;
  out[NTOT*6 + n] = kf;
}

extern "C" void kernel_launch(void* const* d_in,const int* in_sizes,int n_in,
                              void* d_out,int out_size,void* d_ws,size_t ws_size,
                              hipStream_t stream){
  const float* feat=(const float*)d_in[0];
  const float* anchors=(const float*)d_in[1];
  float* out=(float*)d_out;

  char* w=(char*)d_ws;
  auto alloc=[&](size_t bytes)->char*{ char* p=w; w += (bytes+255)&~255ull; return p; };
  float4 *obox =(float4*)alloc(NTOT*16);
  float  *oobj =(float*) alloc(NTOT*4);
  float  *ocls =(float*) alloc(NTOT*4);
  float  *oscore=(float*)alloc(NTOT*4);
  u32    *okey =(u32*)   alloc(NTOT*4);
  int    *rank =(int*)   alloc(NTOT*4);
  float4 *sbox =(float4*)alloc(NTOT*16);
  float  *sarea=(float*) alloc(NTOT*4);
  float  *sobj =(float*) alloc(NTOT*4);
  float  *scls =(float*) alloc(NTOT*4);
  u32    *svalid=(u32*)  alloc(NTOT*4);
  int    *order=(int*)   alloc(NTOT*4);
  u64    *presupG=(u64*) alloc(NW*8);
  u64    *keepw  =(u64*) alloc(NW*8);
  u64    *rowsC  =(u64*) alloc((size_t)NTOT*CWRD*8);   // 1.5 MB intra-chunk rows

  hipLaunchKernelGGL(k_decode, dim3(NTOT/256),dim3(256),0,stream,
                     feat,anchors,obox,oobj,ocls,oscore,okey,rank);
  hipLaunchKernelGGL(k_rank_part, dim3(NTOT/256,12),dim3(256),0,stream, okey,rank);
  hipLaunchKernelGGL(k_scatter, dim3(NTOT/256),dim3(256),0,stream,
                     rank,obox,oobj,ocls,oscore,sbox,sarea,sobj,scls,svalid,order,
                     presupG);
  hipLaunchKernelGGL(k_rowsC, dim3(NTOT/4),dim3(256),0,stream, sbox,sarea,rowsC);
  for(int c=0;c<NCHUNK;c++){
    hipLaunchKernelGGL(k_resolve, dim3(1),dim3(256),0,stream,
                       rowsC,svalid,presupG,keepw,c);
    int rem_blocks = (NTOT-(c+1)*CSZ)/256;
    if(rem_blocks>0)
      hipLaunchKernelGGL(k_fwd, dim3(rem_blocks),dim3(256),0,stream,
                         sbox,sarea,keepw,presupG,c);
  }
  hipLaunchKernelGGL(k_final, dim3(NTOT/256),dim3(256),0,stream,
                     order,keepw,sbox,sobj,scls,out);
}